// Round 8
// baseline (474.123 us; speedup 1.0000x reference)
//
#include <hip/hip_runtime.h>

#define D 128

typedef unsigned int uint;
typedef unsigned short ushort;
typedef unsigned long long ull;

typedef __attribute__((ext_vector_type(8))) short bf16x8;
typedef __attribute__((ext_vector_type(4))) float f32x4;

#define FIXS 33554432.0f           // 2^25
#define FIXM ((1ULL << 40) - 1)

__device__ inline ushort f2bf(float f) {
    uint u = __float_as_uint(f);
    uint r = (u + 0x7fffu + ((u >> 16) & 1u)) >> 16;   // RNE
    return (ushort)r;
}

__device__ inline float bflo(uint g) { return __uint_as_float(g << 16); }
__device__ inline float bfhi(uint g) { return __uint_as_float(g & 0xffff0000u); }

// ---------------- edge pass 1: one packed 64-bit atomic per edge ------------
// packed[c]: bits[39:0] = sum of w (2^-25 fixed pt); bits[63:40] = count.
// Returned old count == this edge's arrival rank within its dst segment.
// (R7 showed XCD-partitioning of this histogram is neutral: device-scope
// fetch-adds serialize at the memory-side coherence point — ~21 G/s floor.)

__global__ __launch_bounds__(256) void k_pass1(const int* __restrict__ col,
                                               const float* __restrict__ w,
                                               ull* __restrict__ packed,
                                               int* __restrict__ rank, int e) {
    int i = blockIdx.x * 256 + threadIdx.x;
    if (i >= e) return;
    int c = col[i];
    ull fx = (ull)(uint)(w[i] * FIXS + 0.5f);
    ull u = atomicAdd(&packed[c], (1ULL << 40) | fx);
    rank[i] = (int)(u >> 40);
}

// ---------------- scan1: dinv + per-block inclusive scan of counts ----------

__global__ __launch_bounds__(256) void k_scan1(const ull* __restrict__ packed,
                                               float* __restrict__ dinv,
                                               int* __restrict__ incl,
                                               int* __restrict__ bsum, int n) {
    int i = blockIdx.x * 256 + threadIdx.x;
    int lane = threadIdx.x & 63;
    int wid  = threadIdx.x >> 6;
    int v = 0;
    if (i < n) {
        ull p = packed[i];
        v = (int)(p >> 40);
        float deg = 1.0f + (float)((double)(p & FIXM) * (1.0 / 33554432.0));
        dinv[i] = rsqrtf(fmaxf(deg, 1e-12f));
    }
    int s = v;
#pragma unroll
    for (int off = 1; off < 64; off <<= 1) {
        int t = __shfl_up(s, off);
        if (lane >= off) s += t;
    }
    __shared__ int wsum[4];
    if (lane == 63) wsum[wid] = s;
    __syncthreads();
    int wo = 0;
    for (int w2 = 0; w2 < wid; ++w2) wo += wsum[w2];
    s += wo;
    if (i < n) incl[i] = s;
    if (threadIdx.x == 255) bsum[blockIdx.x] = s;
}

__global__ __launch_bounds__(256) void k_scan2(const int* __restrict__ bsum,
                                               int* __restrict__ boff, int nb) {
    int i = threadIdx.x;
    int lane = i & 63;
    int wid  = i >> 6;
    int v = (i < nb) ? bsum[i] : 0;
    int s = v;
#pragma unroll
    for (int off = 1; off < 64; off <<= 1) {
        int t = __shfl_up(s, off);
        if (lane >= off) s += t;
    }
    __shared__ int wsum[4];
    if (lane == 63) wsum[wid] = s;
    __syncthreads();
    int wo = 0;
    for (int w2 = 0; w2 < wid; ++w2) wo += wsum[w2];
    s += wo;
    if (i < nb) boff[i] = s - v;   // exclusive
}

__global__ __launch_bounds__(256) void k_scan3(const ull* __restrict__ packed,
                                               const int* __restrict__ incl,
                                               const int* __restrict__ boff,
                                               int* __restrict__ ptr, int n, int e) {
    int i = blockIdx.x * 256 + threadIdx.x;
    if (i > n) return;
    int p;
    if (i == n) p = e;
    else {
        int cnt = (int)(packed[i] >> 40);
        p = incl[i] - cnt + boff[i >> 8];
    }
    ptr[i] = p;
}

// ---------------- edge pass 2: atomic-free CSR fill -------------------------

__global__ __launch_bounds__(256) void k_pass2(const int* __restrict__ row,
                                               const int* __restrict__ col,
                                               const float* __restrict__ w,
                                               const float* __restrict__ dinv,
                                               const int* __restrict__ ptr,
                                               const int* __restrict__ rank,
                                               int2* __restrict__ csr, int e) {
    int i = blockIdx.x * 256 + threadIdx.x;
    if (i >= e) return;
    int r = row[i], c = col[i];
    float v = dinv[r] * w[i];
    csr[ptr[c] + rank[i]] = make_int2(r, __float_as_int(v));
}

// ---------------- MFMA GEMM: xw[n][d] = sum_k h[n][k]*W[d][k], bf16 out -----

#define LDW 136

__global__ __launch_bounds__(256) void k_gemm(const float* __restrict__ h,
                                              const float* __restrict__ W,
                                              ushort* __restrict__ xw, int n) {
    __shared__ ushort Wl[128 * LDW];
    __shared__ ushort Hl[64 * LDW];

    const int t   = threadIdx.x;
    const int gn0 = blockIdx.x * 64;

    for (int i = t; i < 4096; i += 256) {
        int d  = i >> 5;
        int k4 = (i & 31) * 4;
        float4 wv = *(const float4*)(W + d * D + k4);
        ushort4 p;
        p.x = f2bf(wv.x); p.y = f2bf(wv.y); p.z = f2bf(wv.z); p.w = f2bf(wv.w);
        *(ushort4*)(Wl + d * LDW + k4) = p;
    }
    for (int i = t; i < 2048; i += 256) {
        int r  = i >> 5;
        int k4 = (i & 31) * 4;
        int gn = gn0 + r;
        float4 hv = (gn < n) ? *(const float4*)(h + (size_t)gn * D + k4)
                             : make_float4(0.f, 0.f, 0.f, 0.f);
        ushort4 p;
        p.x = f2bf(hv.x); p.y = f2bf(hv.y); p.z = f2bf(hv.z); p.w = f2bf(hv.w);
        *(ushort4*)(Hl + r * LDW + k4) = p;
    }
    __syncthreads();

    const int wave  = t >> 6;
    const int lane  = t & 63;
    const int quad  = lane >> 4;
    const int l15   = lane & 15;
    const int nbase = wave * 32;

    f32x4 acc[4][2];
#pragma unroll
    for (int mt = 0; mt < 4; ++mt)
#pragma unroll
        for (int nt = 0; nt < 2; ++nt) acc[mt][nt] = (f32x4)(0.0f);

#pragma unroll
    for (int kc = 0; kc < 4; ++kc) {
        int ko = kc * 32 + quad * 8;
        bf16x8 a[4], b[2];
#pragma unroll
        for (int mt = 0; mt < 4; ++mt)
            a[mt] = *(const bf16x8*)(Hl + (mt * 16 + l15) * LDW + ko);
#pragma unroll
        for (int nt = 0; nt < 2; ++nt)
            b[nt] = *(const bf16x8*)(Wl + (nbase + nt * 16 + l15) * LDW + ko);
#pragma unroll
        for (int mt = 0; mt < 4; ++mt)
#pragma unroll
            for (int nt = 0; nt < 2; ++nt)
                acc[mt][nt] = __builtin_amdgcn_mfma_f32_16x16x32_bf16(
                    a[mt], b[nt], acc[mt][nt], 0, 0, 0);
    }
    __syncthreads();

#pragma unroll
    for (int mt = 0; mt < 4; ++mt)
#pragma unroll
        for (int nt = 0; nt < 2; ++nt)
#pragma unroll
            for (int r = 0; r < 4; ++r)
                Hl[(mt * 16 + quad * 4 + r) * LDW + nbase + nt * 16 + l15] =
                    f2bf(acc[mt][nt][r]);
    __syncthreads();

    for (int i = t; i < 1024; i += 256) {
        int r = i >> 4, seg = i & 15;
        int gn = gn0 + r;
        if (gn < n) {
            uint4 v = *(const uint4*)(Hl + r * LDW + seg * 8);
            *(uint4*)(xw + (size_t)gn * D + seg * 8) = v;
        }
    }
}

// ---------------- fused pull-aggregate + bias + LN + ReLU + residual --------
// One 64-lane wave per node. Lanes 0-31 / 32-63 take CONTIGUOUS halves of the
// node's CSR segment (csr loads within an iter share cache lines), 4 features
// per lane (uint2 gathers), 8 independent row-gathers in flight per half.

__global__ __launch_bounds__(256) void k_pull_ln(const ushort* __restrict__ xw,
                                                 const int* __restrict__ ptr,
                                                 const int2* __restrict__ csr,
                                                 const float* __restrict__ dinv,
                                                 const float* __restrict__ bias,
                                                 const float* __restrict__ gamma,
                                                 const float* __restrict__ beta,
                                                 const float* __restrict__ identity,
                                                 float* __restrict__ hout,
                                                 int n, int relu) {
    int node = blockIdx.x * 4 + (threadIdx.x >> 6);
    if (node >= n) return;
    int lane = threadIdx.x & 63;
    int half = lane >> 5;
    int l    = lane & 31;
    int o    = l * 4;

    float a0 = 0.f, a1 = 0.f, a2 = 0.f, a3 = 0.f;

    int ebeg = ptr[node];
    int eend = ptr[node + 1];
    int len  = eend - ebeg;
    int h0   = (len + 1) >> 1;
    int e     = half ? (ebeg + h0) : ebeg;
    int estop = half ? eend : (ebeg + h0);

    for (; e + 7 < estop; e += 8) {
        int2 c0 = csr[e],     c1 = csr[e + 1], c2 = csr[e + 2], c3 = csr[e + 3];
        int2 c4 = csr[e + 4], c5 = csr[e + 5], c6 = csr[e + 6], c7 = csr[e + 7];
        uint2 g0 = *(const uint2*)(xw + (size_t)c0.x * D + o);
        uint2 g1 = *(const uint2*)(xw + (size_t)c1.x * D + o);
        uint2 g2 = *(const uint2*)(xw + (size_t)c2.x * D + o);
        uint2 g3 = *(const uint2*)(xw + (size_t)c3.x * D + o);
        uint2 g4 = *(const uint2*)(xw + (size_t)c4.x * D + o);
        uint2 g5 = *(const uint2*)(xw + (size_t)c5.x * D + o);
        uint2 g6 = *(const uint2*)(xw + (size_t)c6.x * D + o);
        uint2 g7 = *(const uint2*)(xw + (size_t)c7.x * D + o);
        float n0 = __int_as_float(c0.y), n1 = __int_as_float(c1.y);
        float n2 = __int_as_float(c2.y), n3 = __int_as_float(c3.y);
        float n4 = __int_as_float(c4.y), n5 = __int_as_float(c5.y);
        float n6 = __int_as_float(c6.y), n7 = __int_as_float(c7.y);
        a0 += n0 * bflo(g0.x) + n1 * bflo(g1.x) + n2 * bflo(g2.x) + n3 * bflo(g3.x);
        a1 += n0 * bfhi(g0.x) + n1 * bfhi(g1.x) + n2 * bfhi(g2.x) + n3 * bfhi(g3.x);
        a2 += n0 * bflo(g0.y) + n1 * bflo(g1.y) + n2 * bflo(g2.y) + n3 * bflo(g3.y);
        a3 += n0 * bfhi(g0.y) + n1 * bfhi(g1.y) + n2 * bfhi(g2.y) + n3 * bfhi(g3.y);
        a0 += n4 * bflo(g4.x) + n5 * bflo(g5.x) + n6 * bflo(g6.x) + n7 * bflo(g7.x);
        a1 += n4 * bfhi(g4.x) + n5 * bfhi(g5.x) + n6 * bfhi(g6.x) + n7 * bfhi(g7.x);
        a2 += n4 * bflo(g4.y) + n5 * bflo(g5.y) + n6 * bflo(g6.y) + n7 * bflo(g7.y);
        a3 += n4 * bfhi(g4.y) + n5 * bfhi(g5.y) + n6 * bfhi(g6.y) + n7 * bfhi(g7.y);
    }
    for (; e < estop; ++e) {
        int2 c0 = csr[e];
        uint2 g0 = *(const uint2*)(xw + (size_t)c0.x * D + o);
        float n0 = __int_as_float(c0.y);
        a0 += n0 * bflo(g0.x);
        a1 += n0 * bfhi(g0.x);
        a2 += n0 * bflo(g0.y);
        a3 += n0 * bfhi(g0.y);
    }

    a0 += __shfl_xor(a0, 32);
    a1 += __shfl_xor(a1, 32);
    a2 += __shfl_xor(a2, 32);
    a3 += __shfl_xor(a3, 32);

    float di = dinv[node];
    uint2 ps = *(const uint2*)(xw + (size_t)node * D + o);
    float4 bb = *(const float4*)(bias + o);
    a0 = bb.x + di * (di * bflo(ps.x) + a0);
    a1 = bb.y + di * (di * bfhi(ps.x) + a1);
    a2 = bb.z + di * (di * bflo(ps.y) + a2);
    a3 = bb.w + di * (di * bfhi(ps.y) + a3);

    // LayerNorm over 128 features: reduce across 32 lanes (halves identical)
    float s = (a0 + a1) + (a2 + a3);
#pragma unroll
    for (int off = 16; off; off >>= 1) s += __shfl_xor(s, off);
    float mu = s * (1.0f / 128.0f);
    float d0 = a0 - mu, d1 = a1 - mu, d2 = a2 - mu, d3 = a3 - mu;
    float vs = (d0 * d0 + d1 * d1) + (d2 * d2 + d3 * d3);
#pragma unroll
    for (int off = 16; off; off >>= 1) vs += __shfl_xor(vs, off);
    float rs = rsqrtf(vs * (1.0f / 128.0f) + 1e-5f);

    float4 g  = *(const float4*)(gamma + o);
    float4 b2 = *(const float4*)(beta + o);
    float4 id = *(const float4*)(identity + (size_t)node * D + o);
    float o0 = d0 * rs * g.x + b2.x;
    float o1 = d1 * rs * g.y + b2.y;
    float o2 = d2 * rs * g.z + b2.z;
    float o3 = d3 * rs * g.w + b2.w;
    if (relu) {
        o0 = fmaxf(o0, 0.0f); o1 = fmaxf(o1, 0.0f);
        o2 = fmaxf(o2, 0.0f); o3 = fmaxf(o3, 0.0f);
    }
    if (half == 0)
        *(float4*)(hout + (size_t)node * D + o) =
            make_float4(o0 + id.x, o1 + id.y, o2 + id.z, o3 + id.w);
}

// ---------------- launch ----------------

extern "C" void kernel_launch(void* const* d_in, const int* in_sizes, int n_in,
                              void* d_out, int out_size, void* d_ws, size_t ws_size,
                              hipStream_t stream) {
    const float* x      = (const float*)d_in[0];
    const int*   ei     = (const int*)d_in[1];
    const float* ew     = (const float*)d_in[2];
    const float* Ws     = (const float*)d_in[3];
    const float* bs     = (const float*)d_in[4];
    const float* gammas = (const float*)d_in[5];
    const float* betas  = (const float*)d_in[6];
    float* out = (float*)d_out;

    const int N = in_sizes[0] / D;
    const int E = in_sizes[2];
    const int* row = ei;
    const int* col = ei + E;

    // workspace layout (8-byte types first)
    char* w8 = (char*)d_ws;
    ull*   packed = (ull*)w8;    w8 += sizeof(ull) * N;
    int2*  csr    = (int2*)w8;   w8 += sizeof(int2) * E;
    float* dinv   = (float*)w8;  w8 += sizeof(float) * N;
    int*   incl   = (int*)w8;    w8 += sizeof(int) * N;
    int*   bsum   = (int*)w8;    w8 += sizeof(int) * 256;
    int*   boff   = (int*)w8;    w8 += sizeof(int) * 256;
    int*   ptr    = (int*)w8;    w8 += sizeof(int) * (N + 1);
    int*   rank   = (int*)w8;    w8 += sizeof(int) * E;
    float* buf1   = (float*)w8;  w8 += sizeof(float) * (size_t)N * D;
    ushort* xwb   = (ushort*)w8; w8 += sizeof(ushort) * (size_t)N * D;

    dim3 blk(256);
    int gN1   = (N + 256) / 256;
    int gE    = (E + 255) / 256;
    int nb    = (N + 255) / 256;
    int gGemm = (N + 63) / 64;
    int gPull = (N + 3) / 4;

    hipMemsetAsync(packed, 0, sizeof(ull) * N, stream);
    k_pass1<<<gE, blk, 0, stream>>>(col, ew, packed, rank, E);
    k_scan1<<<nb, blk, 0, stream>>>(packed, dinv, incl, bsum, N);
    k_scan2<<<1, blk, 0, stream>>>(bsum, boff, nb);
    k_scan3<<<gN1, blk, 0, stream>>>(packed, incl, boff, ptr, N, E);
    k_pass2<<<gE, blk, 0, stream>>>(row, col, ew, dinv, ptr, rank, csr, E);

    // layer 0: h = x -> out
    k_gemm<<<gGemm, blk, 0, stream>>>(x, Ws, xwb, N);
    k_pull_ln<<<gPull, blk, 0, stream>>>(xwb, ptr, csr, dinv,
                                         bs, gammas, betas, x, out, N, 1);
    // layer 1: h = out -> buf1
    k_gemm<<<gGemm, blk, 0, stream>>>(out, Ws + 16384, xwb, N);
    k_pull_ln<<<gPull, blk, 0, stream>>>(xwb, ptr, csr, dinv,
                                         bs + D, gammas + D, betas + D, out, buf1, N, 1);
    // layer 2: h = buf1 -> out
    k_gemm<<<gGemm, blk, 0, stream>>>(buf1, Ws + 32768, xwb, N);
    k_pull_ln<<<gPull, blk, 0, stream>>>(xwb, ptr, csr, dinv,
                                         bs + 2 * D, gammas + 2 * D, betas + 2 * D,
                                         buf1, out, N, 0);
}